// Round 2
// baseline (230.289 us; speedup 1.0000x reference)
//
#include <hip/hip_runtime.h>

#define NFFT 1024

// ---------- complex helpers ----------
__device__ __forceinline__ float2 cmul(float2 a, float2 b) {
  return make_float2(fmaf(a.x, b.x, -a.y * b.y), fmaf(a.x, b.y, a.y * b.x));
}
__device__ __forceinline__ float2 cadd(float2 a, float2 b) { return make_float2(a.x + b.x, a.y + b.y); }
__device__ __forceinline__ float2 csub(float2 a, float2 b) { return make_float2(a.x - b.x, a.y - b.y); }

// y_k = sum_r v_r * e^{-2*pi*i*k*r/4}
__device__ __forceinline__ void dft4(const float2 v[4], float2 y[4]) {
  float2 s02 = cadd(v[0], v[2]), d02 = csub(v[0], v[2]);
  float2 s13 = cadd(v[1], v[3]), d13 = csub(v[1], v[3]);
  y[0] = cadd(s02, s13);
  y[2] = csub(s02, s13);
  y[1] = make_float2(d02.x + d13.y, d02.y - d13.x);  // d02 + (-i)*d13
  y[3] = make_float2(d02.x - d13.y, d02.y + d13.x);  // d02 + (+i)*d13
}

// LDS slot swizzle: rotate the low-16 window by the window index. Bijective;
// makes every wave64 ds_*_b64 access spread 4 lanes/bank = conflict-free floor.
__device__ __forceinline__ int phys(int s) {
  return (s & ~15) | (((s & 15) + (s >> 4)) & 15);
}

// In-register 16-point forward DFT (X[k] = sum_n v[n] W16^{nk}), then store
// X[k] to S[phys(base + stride*k)].  Decomposition: DFT4 (n1) -> const
// twiddles W16^{n2*k1} -> DFT4 (n2).  All twiddles compile-time constants.
__device__ __forceinline__ void dft16_store(float2 v[16], float2* S, int base, int stride) {
  // Step A: for each n2, DFT4 over n1 (stride 4); result -> slot n2+4*k1
  #pragma unroll
  for (int n2 = 0; n2 < 4; ++n2) {
    float2 a[4] = {v[n2], v[n2 + 4], v[n2 + 8], v[n2 + 12]};
    float2 y[4];
    dft4(a, y);
    v[n2] = y[0]; v[n2 + 4] = y[1]; v[n2 + 8] = y[2]; v[n2 + 12] = y[3];
  }
  // Step B: multiply slot n2+4*k1 by W16^{n2*k1}
  const float C1 = 0.9238795325112867f;   // cos(pi/8)
  const float S1 = 0.3826834323650898f;   // sin(pi/8)
  const float R2 = 0.7071067811865476f;   // sqrt(2)/2
  v[1 + 4]  = cmul(v[1 + 4],  make_float2(C1, -S1));    // W^1
  v[1 + 8]  = cmul(v[1 + 8],  make_float2(R2, -R2));    // W^2
  v[1 + 12] = cmul(v[1 + 12], make_float2(S1, -C1));    // W^3
  v[2 + 4]  = cmul(v[2 + 4],  make_float2(R2, -R2));    // W^2
  v[2 + 8]  = make_float2(v[2 + 8].y, -v[2 + 8].x);     // W^4 = -i
  v[2 + 12] = cmul(v[2 + 12], make_float2(-R2, -R2));   // W^6
  v[3 + 4]  = cmul(v[3 + 4],  make_float2(S1, -C1));    // W^3
  v[3 + 8]  = cmul(v[3 + 8],  make_float2(-R2, -R2));   // W^6
  v[3 + 12] = cmul(v[3 + 12], make_float2(-C1, S1));    // W^9
  // Step C: for each k1, DFT4 over n2 (slots 4k1..4k1+3) -> X[k1+4*k2]
  #pragma unroll
  for (int k1 = 0; k1 < 4; ++k1) {
    float2 a[4] = {v[4 * k1], v[4 * k1 + 1], v[4 * k1 + 2], v[4 * k1 + 3]};
    float2 y[4];
    dft4(a, y);
    #pragma unroll
    for (int k2 = 0; k2 < 4; ++k2) {
      int k = k1 + 4 * k2;
      S[phys(base + stride * k)] = y[k2];
    }
  }
}

// Stockham FFT N=1024 = 16*16*4, one WAVE per row, 16 points/lane.
// 3 passes, 2 LDS round-trips, no __syncthreads (wave-private LDS region;
// intra-wave LDS ops are program-ordered and every DFT output depends on all
// 16 reads, so read-before-overwrite is enforced by data deps).
__global__ __launch_bounds__(256) void fft1024_kernel(const float* __restrict__ in,
                                                      float* __restrict__ out) {
  __shared__ float2 lds[4 * NFFT];           // 8 KB per wave, 32 KB per block
  const int wave = threadIdx.x >> 6;
  const int l    = threadIdx.x & 63;
  float2* S = lds + wave * NFFT;
  const int row = blockIdx.x * 4 + wave;
  const float2* xin  = reinterpret_cast<const float2*>(in)  + (size_t)row * NFFT;
  float2*       xout = reinterpret_cast<float2*>(out)       + (size_t)row * NFFT;

  float2 v[16];

  // ---- pass 0: Ns=1, R=16. global -> regs -> LDS.  No twiddle.
  #pragma unroll
  for (int r = 0; r < 16; ++r) v[r] = xin[l + 64 * r];   // coalesced b64
  dft16_store(v, S, 16 * l, 1);                          // out slot = 16l + k

  // ---- pass 1: Ns=16, R=16. LDS -> regs -> LDS.
  #pragma unroll
  for (int r = 0; r < 16; ++r) v[r] = S[phys(l + 64 * r)];
  {
    const float ang = -6.283185307179586f * (float)(l & 15) / 256.0f;
    float sn, cs;
    __sincosf(ang, &sn, &cs);
    const float2 w1 = make_float2(cs, sn);
    float2 w = w1;
    #pragma unroll
    for (int r = 1; r < 16; ++r) {       // v[r] *= w1^r  (incremental powers)
      v[r] = cmul(v[r], w);
      w = cmul(w, w1);
    }
    const int idxD = ((l >> 4) << 8) | (l & 15);   // (l/16)*256 + l%16
    dft16_store(v, S, idxD, 16);                   // out slot = idxD + 16k
  }

  // ---- pass 2: Ns=256, R=4. LDS -> regs -> global (coalesced).
  #pragma unroll
  for (int t = 0; t < 4; ++t) {
    const int j = l + 64 * t;
    float2 u[4];
    #pragma unroll
    for (int r = 0; r < 4; ++r) u[r] = S[phys(j + 256 * r)];
    const float ang = -6.283185307179586f * (float)j / 1024.0f;
    float sn, cs;
    __sincosf(ang, &sn, &cs);
    const float2 w1 = make_float2(cs, sn);
    const float2 w2 = cmul(w1, w1);
    const float2 w3 = cmul(w2, w1);
    u[1] = cmul(u[1], w1);
    u[2] = cmul(u[2], w2);
    u[3] = cmul(u[3], w3);
    float2 y[4];
    dft4(u, y);
    #pragma unroll
    for (int r = 0; r < 4; ++r) xout[j + 256 * r] = y[r];
  }
}

extern "C" void kernel_launch(void* const* d_in, const int* in_sizes, int n_in,
                              void* d_out, int out_size, void* d_ws, size_t ws_size,
                              hipStream_t stream) {
  const float* x = (const float*)d_in[0];
  float* out = (float*)d_out;
  const int rows = in_sizes[0] / (2 * NFFT);   // 16384 rows of 1024 complex
  fft1024_kernel<<<rows / 4, 256, 0, stream>>>(x, out);
}

// Round 3
// 224.129 us; speedup vs baseline: 1.0275x; 1.0275x over previous
//
#include <hip/hip_runtime.h>

#define TPB 256
#define NFFT 1024

// XOR swizzle: bijective; breaks power-of-2 stride bank patterns.
// Verified 0 SQ_LDS_BANK_CONFLICT in rounds 1-2.
__device__ __forceinline__ int sw(int i) { return i ^ ((i >> 5) & 31); }

__device__ __forceinline__ float2 cmul(float2 a, float2 b) {
  return make_float2(fmaf(a.x, b.x, -a.y * b.y), fmaf(a.x, b.y, a.y * b.x));
}
__device__ __forceinline__ float2 cadd(float2 a, float2 b) { return make_float2(a.x + b.x, a.y + b.y); }
__device__ __forceinline__ float2 csub(float2 a, float2 b) { return make_float2(a.x - b.x, a.y - b.y); }

// y_k = sum_r v_r * e^{-2*pi*i*k*r/4}
__device__ __forceinline__ void dft4(const float2 v[4], float2 y[4]) {
  float2 s02 = cadd(v[0], v[2]), d02 = csub(v[0], v[2]);
  float2 s13 = cadd(v[1], v[3]), d13 = csub(v[1], v[3]);
  y[0] = cadd(s02, s13);
  y[2] = csub(s02, s13);
  y[1] = make_float2(d02.x + d13.y, d02.y - d13.x);  // d02 + (-i)*d13
  y[3] = make_float2(d02.x - d13.y, d02.y + d13.x);  // d02 + (+i)*d13
}

// Stockham radix-4, N=1024, one block per row, 4 points/thread.
// SINGLE 8 KB LDS buffer (2 KB/wave) -> 8 blocks/CU, 32 waves/CU resident.
// 7 barriers/row; cross-block overlap hides barrier drains.
__global__ __launch_bounds__(TPB, 8) void fft1024_kernel(const float* __restrict__ in,
                                                         float* __restrict__ out) {
  __shared__ float2 buf[NFFT];   // 8 KB
  const int j = threadIdx.x;
  const float2* xin  = reinterpret_cast<const float2*>(in)  + (size_t)blockIdx.x * NFFT;
  float2*       xout = reinterpret_cast<float2*>(out)       + (size_t)blockIdx.x * NFFT;

  float2 v[4], y[4];

  // ---- pass 0: Ns=1 (no twiddle). global -> LDS
  #pragma unroll
  for (int r = 0; r < 4; ++r) v[r] = xin[j + 256 * r];
  dft4(v, y);
  #pragma unroll
  for (int r = 0; r < 4; ++r) buf[sw(4 * j + r)] = y[r];
  __syncthreads();

  // ---- pass 1: Ns=4. Twiddles from a constant 4-entry set (no sincos).
  {
    #pragma unroll
    for (int r = 0; r < 4; ++r) v[r] = buf[sw(j + 256 * r)];
    __syncthreads();           // all reads done before overwrite
    const int t = j & 3;
    // w1 = exp(-2*pi*i*t/16)
    const float C1 = 0.9238795325112867f, S1 = 0.3826834323650898f;
    const float R2 = 0.7071067811865476f;
    float2 w1;
    w1.x = (t == 0) ? 1.0f : (t == 1) ? C1 : (t == 2) ? R2 : S1;
    w1.y = (t == 0) ? 0.0f : (t == 1) ? -S1 : (t == 2) ? -R2 : -C1;
    float2 w2 = cmul(w1, w1);
    float2 w3 = cmul(w2, w1);
    v[1] = cmul(v[1], w1);
    v[2] = cmul(v[2], w2);
    v[3] = cmul(v[3], w3);
    dft4(v, y);
    const int idxD = ((j & ~3) << 2) | (j & 3);
    #pragma unroll
    for (int r = 0; r < 4; ++r) buf[sw(idxD + 4 * r)] = y[r];
    __syncthreads();
  }

  // ---- passes 2,3: Ns=16,64. sincos twiddles.
  #pragma unroll
  for (int p = 2; p <= 3; ++p) {
    const int Ns = 1 << (2 * p);
    #pragma unroll
    for (int r = 0; r < 4; ++r) v[r] = buf[sw(j + 256 * r)];
    __syncthreads();           // reads before overwrite
    const float ang = -6.283185307179586f * (float)(j & (Ns - 1)) / (float)(4 * Ns);
    float sn, cs;
    __sincosf(ang, &sn, &cs);
    float2 w1 = make_float2(cs, sn);
    float2 w2 = cmul(w1, w1);
    float2 w3 = cmul(w2, w1);
    v[1] = cmul(v[1], w1);
    v[2] = cmul(v[2], w2);
    v[3] = cmul(v[3], w3);
    dft4(v, y);
    const int idxD = ((j & ~(Ns - 1)) << 2) | (j & (Ns - 1));
    #pragma unroll
    for (int r = 0; r < 4; ++r) buf[sw(idxD + r * Ns)] = y[r];
    __syncthreads();
  }

  // ---- pass 4: Ns=256. LDS -> global (coalesced, idxD == j).
  {
    #pragma unroll
    for (int r = 0; r < 4; ++r) v[r] = buf[sw(j + 256 * r)];
    const int Ns = 256;
    const float ang = -6.283185307179586f * (float)(j & (Ns - 1)) / (float)(4 * Ns);
    float sn, cs;
    __sincosf(ang, &sn, &cs);
    float2 w1 = make_float2(cs, sn);
    float2 w2 = cmul(w1, w1);
    float2 w3 = cmul(w2, w1);
    v[1] = cmul(v[1], w1);
    v[2] = cmul(v[2], w2);
    v[3] = cmul(v[3], w3);
    dft4(v, y);
    #pragma unroll
    for (int r = 0; r < 4; ++r) xout[j + 256 * r] = y[r];
  }
}

extern "C" void kernel_launch(void* const* d_in, const int* in_sizes, int n_in,
                              void* d_out, int out_size, void* d_ws, size_t ws_size,
                              hipStream_t stream) {
  const float* x = (const float*)d_in[0];
  float* out = (float*)d_out;
  const int rows = in_sizes[0] / (2 * NFFT);   // 16384 rows of 1024 complex
  fft1024_kernel<<<rows, TPB, 0, stream>>>(x, out);
}